// Round 2
// baseline (106.506 us; speedup 1.0000x reference)
//
#include <hip/hip_runtime.h>

#define T 32
#define BLOCK 256
#define GRID 2048

typedef float v4f __attribute__((ext_vector_type(4)));

// Fused: swizzled global->LDS staging (perfectly coalesced), per-row scan,
// deterministic fixed-point atomic reduction, last block writes the loss.
__global__ __launch_bounds__(BLOCK) void mel_fused(const float* __restrict__ probs,
                                                   int nrows, int nlaunched,
                                                   unsigned long long* __restrict__ ws,
                                                   float* __restrict__ out) {
    __shared__ float lds[BLOCK * T];     // 32 KB: 256 rows x 128 B, XOR-swizzled segs
    __shared__ double sred[BLOCK / 64];

    const int t = threadIdx.x;
    const int w = t >> 6;                // wave id (0..3)
    const int l = t & 63;                // lane
    const int nchunks = (nrows + BLOCK - 1) / BLOCK;
    const long long maxf4 = (long long)nrows * (T / 4) - 1;

    // gload_lds instr k of wave w fills slots u = (w*8+k)*64 + l (16 B each).
    // Layout: slot u <- row(u)=u>>3, seg(u) = (u&7) ^ (row(u)&7).
    const int lrow8 = l >> 3;            // row-within-8 for this lane
    const int lseg  = (l & 7) ^ lrow8;   // swizzled segment this lane fetches
    const int sw    = t & 7;             // read-side swizzle for own row
    const int rbase = t * T;             // float offset of own row in LDS

    double acc = 0.0;

    for (int c = blockIdx.x; c < nchunks; c += gridDim.x) {
        const long long chunkF4 = (long long)c * BLOCK * (T / 4);

        // ---- stage 64 rows per wave into wave-private LDS (no barrier needed) ----
        #pragma unroll
        for (int k = 0; k < 8; ++k) {
            long long srcF4 = chunkF4 + (long long)((w * 64 + k * 8 + lrow8) * 8 + lseg);
            if (srcF4 > maxf4) srcF4 = maxf4;   // tail clamp: valid dup reads
            __builtin_amdgcn_global_load_lds(
                (const __attribute__((address_space(1))) void*)((const v4f*)probs + srcF4),
                (__attribute__((address_space(3))) void*)&lds[(w * 8 + k) * 256],
                16, 0, 0);
        }
        asm volatile("s_waitcnt vmcnt(0)" ::: "memory");

        // ---- row t of this chunk: identical arithmetic order to round 1 ----
        float p[T];
        #pragma unroll
        for (int i = 0; i < T / 4; ++i) {
            v4f v = *(const v4f*)&lds[rbase + 4 * (i ^ sw)];
            p[4 * i + 0] = v[0];
            p[4 * i + 1] = v[1];
            p[4 * i + 2] = v[2];
            p[4 * i + 3] = v[3];
        }

        float suf[T];
        suf[T - 1] = 1.0f;
        #pragma unroll
        for (int i = T - 2; i >= 0; --i) suf[i] = suf[i + 1] * (1.0f - p[i + 1]);

        float pre = 1.0f, s = 0.0f;
        #pragma unroll
        for (int i = 0; i < T; ++i) {
            float q = pre * suf[i];
            s = (s + p[i]) * q;
            pre *= (1.0f - p[i]);
        }

        if ((long long)c * BLOCK + t < nrows) acc += (double)s;
    }

    // ---- block reduction (deterministic) ----
    #pragma unroll
    for (int off = 32; off > 0; off >>= 1) acc += __shfl_down(acc, off, 64);
    if (l == 0) sred[w] = acc;
    __syncthreads();
    if (t == 0) {
        double b = sred[0] + sred[1] + sred[2] + sred[3];
        // fixed-point 2^36: integer atomics commute exactly -> deterministic
        long long fx = __double2ll_rn(b * 68719476736.0);
        atomicAdd(ws, (unsigned long long)fx);
        __threadfence();
        unsigned int old = atomicAdd((unsigned int*)(ws + 1), 1u);
        if (old == (unsigned int)(nlaunched - 1)) {
            __threadfence();
            unsigned long long tot = atomicAdd(ws, 0ULL);
            double total = (double)(long long)tot * (1.0 / 68719476736.0);
            out[0] = (float)(-total / (double)nrows);
        }
    }
}

extern "C" void kernel_launch(void* const* d_in, const int* in_sizes, int n_in,
                              void* d_out, int out_size, void* d_ws, size_t ws_size,
                              hipStream_t stream) {
    const float* probs = (const float*)d_in[0];
    float* out = (float*)d_out;
    const int nrows = in_sizes[0] / T;
    const int nchunks = (nrows + BLOCK - 1) / BLOCK;
    const int grid = (GRID < nchunks) ? GRID : nchunks;

    hipMemsetAsync(d_ws, 0, 16, stream);   // zero acc + counter (graph-safe)
    mel_fused<<<grid, BLOCK, 0, stream>>>(probs, nrows, grid,
                                          (unsigned long long*)d_ws, out);
}